// Round 1
// baseline (244.527 us; speedup 1.0000x reference)
//
#include <hip/hip_runtime.h>

// Problem constants (from reference: B=8, N=8192, M=2500, P=10)
#define B_   8
#define N_   8192
#define M_   2500
#define P_   10
#define SPP_ 250
#define EPS_ 1e-20f

// ws layout (floats):
//   [0 .. 19999]        p2gt per-(b,m) min d^2    (20000)
//   [20000 .. 85535]    gt2p per-(b,n) min d^2    (65536)
//   [85536 .. ]         scalar accumulators
#define WS_P2GT   0
#define WS_GT2P   20000
#define WS_ACC    85536
// accumulator slots
#define A_SUM_P2GT 0
#define A_SUM_GT2P 1
#define A_SUM_E    2
#define A_SUM_G    3
#define A_SUM_MC   4
#define A_SUM_ST   5
#define A_SUM_F    6
#define A_SUM_EC   7
#define A_SUM_GC   8
#define A_ASUM0    9   // 9..16 : per-batch sum of A
#define ACC_COUNT  17

__device__ __forceinline__ float wave_sum64(float v) {
    #pragma unroll
    for (int o = 32; o > 0; o >>= 1) v += __shfl_down(v, o, 64);
    return v;
}

// Block sum over 256 threads (4 waves). Result valid on thread 0.
__device__ __forceinline__ float block_sum256(float v, float* red4) {
    v = wave_sum64(v);
    int wid  = threadIdx.x >> 6;
    int lane = threadIdx.x & 63;
    if (lane == 0) red4[wid] = v;
    __syncthreads();
    float r = 0.f;
    if (threadIdx.x == 0) r = red4[0] + red4[1] + red4[2] + red4[3];
    __syncthreads();  // red4 reusable after return
    return r;
}

// ---- Chamfer: pred -> nearest gt ------------------------------------------
// grid (ceil(M/256)=10, B=8, 8 z-chunks of 1024 gt), block 256
__global__ void chamfer_p2gt(const float* __restrict__ gt,
                             const float* __restrict__ pred,
                             float* __restrict__ mins) {
    __shared__ float4 sg[1024];
    const int b = blockIdx.y;
    const int z = blockIdx.z;
    const int m = blockIdx.x * 256 + threadIdx.x;

    const float* gtb = gt + ((size_t)b * N_ + (size_t)z * 1024) * 3;
    for (int i = threadIdx.x; i < 1024; i += 256) {
        float gx = gtb[i * 3 + 0];
        float gy = gtb[i * 3 + 1];
        float gz = gtb[i * 3 + 2];
        sg[i] = make_float4(gx, gy, gz, gx * gx + gy * gy + gz * gz);
    }
    __syncthreads();

    if (m < M_) {
        const float* p = pred + ((size_t)b * M_ + m) * 3;
        float px = p[0], py = p[1], pz = p[2];
        float pn = px * px + py * py + pz * pz;
        float best = 3.4e38f;
        #pragma unroll 8
        for (int i = 0; i < 1024; ++i) {
            float4 g = sg[i];
            float t  = fmaf(g.x, px, fmaf(g.y, py, g.z * pz));
            float v  = fmaf(-2.f, t, g.w);   // |g|^2 - 2 p.g
            best = fminf(best, v);
        }
        float d = fmaxf(best + pn, 0.f);     // full squared distance, >= 0
        atomicMin((unsigned int*)&mins[b * M_ + m], __float_as_uint(d));
    }
}

// ---- Chamfer: gt -> nearest pred ------------------------------------------
// grid (N/256=32, B=8, 4 z-chunks of 625 preds), block 256
__global__ void chamfer_gt2p(const float* __restrict__ gt,
                             const float* __restrict__ pred,
                             float* __restrict__ mins) {
    __shared__ float4 sp[625];
    const int b = blockIdx.y;
    const int z = blockIdx.z;
    const int n = blockIdx.x * 256 + threadIdx.x;   // always < 8192

    const float* pb = pred + ((size_t)b * M_ + (size_t)z * 625) * 3;
    for (int i = threadIdx.x; i < 625; i += 256) {
        float x = pb[i * 3 + 0];
        float y = pb[i * 3 + 1];
        float w = pb[i * 3 + 2];
        sp[i] = make_float4(x, y, w, x * x + y * y + w * w);
    }
    __syncthreads();

    const float* g = gt + ((size_t)b * N_ + n) * 3;
    float gx = g[0], gy = g[1], gz = g[2];
    float gn = gx * gx + gy * gy + gz * gz;
    float best = 3.4e38f;
    #pragma unroll 8
    for (int i = 0; i < 625; ++i) {
        float4 p = sp[i];
        float t  = fmaf(p.x, gx, fmaf(p.y, gy, p.z * gz));
        float v  = fmaf(-2.f, t, p.w);
        best = fminf(best, v);
    }
    float d = fmaxf(best + gn, 0.f);
    atomicMin((unsigned int*)&mins[b * N_ + n], __float_as_uint(d));
}

// ---- sum the two min arrays -----------------------------------------------
__global__ void reduce_mins(const float* __restrict__ mins, float* __restrict__ acc) {
    __shared__ float red4[4];
    float s0 = 0.f, s1 = 0.f;
    for (int i = blockIdx.x * blockDim.x + threadIdx.x; i < 85536;
         i += gridDim.x * blockDim.x) {
        float v = mins[i];
        if (i < 20000) s0 += v; else s1 += v;
    }
    float b0 = block_sum256(s0, red4);
    float b1 = block_sum256(s1, red4);
    if (threadIdx.x == 0) {
        atomicAdd(&acc[A_SUM_P2GT], b0);
        atomicAdd(&acc[A_SUM_GT2P], b1);
    }
}

// ---- FFF pass 1: everything not needing global means ----------------------
// grid ceil(20000/256)=79
__global__ void fff_pass1(const float* __restrict__ fff, float* __restrict__ acc) {
    __shared__ float red4[4];
    __shared__ float sA[B_];
    const int idx = blockIdx.x * 256 + threadIdx.x;

    if (threadIdx.x < B_) sA[threadIdx.x] = 0.f;
    __syncthreads();

    float sE = 0.f, sG = 0.f, sMC = 0.f, sST = 0.f, sF = 0.f;
    if (idx < B_ * M_) {
        const int b = idx / M_;
        const int m = idx - b * M_;
        const float* f = fff + (size_t)idx * 3;
        float E = f[0], F = f[1], G = f[2];
        sE = E; sG = G;
        float A2  = fmaxf(E * G - F * F, 0.f);
        float inv = 1.f / (A2 + EPS_);
        sST = (E - G) * (E - G) * inv;
        sF  = F * F * inv;
        atomicAdd(&sA[b], sqrtf(A2));
        if ((b & 1) == 0) {
            const float* f2 = fff + ((size_t)(b + 1) * M_ + m) * 3;
            float dE = E - f2[0], dF = F - f2[1], dG = G - f2[2];
            sMC = dE * dE + 2.f * dF * dF + dG * dG;
        }
    }
    float rE  = block_sum256(sE, red4);
    float rG  = block_sum256(sG, red4);
    float rMC = block_sum256(sMC, red4);
    float rST = block_sum256(sST, red4);
    float rF  = block_sum256(sF, red4);
    if (threadIdx.x == 0) {
        atomicAdd(&acc[A_SUM_E],  rE);
        atomicAdd(&acc[A_SUM_G],  rG);
        atomicAdd(&acc[A_SUM_MC], rMC);
        atomicAdd(&acc[A_SUM_ST], rST);
        atomicAdd(&acc[A_SUM_F],  rF);
    }
    __syncthreads();  // all sA atomics done
    if (threadIdx.x < B_ && sA[threadIdx.x] != 0.f)
        atomicAdd(&acc[A_ASUM0 + threadIdx.x], sA[threadIdx.x]);
}

// ---- FFF pass 2: centered E/G terms (needs global means from pass 1) ------
__global__ void fff_pass2(const float* __restrict__ fff, float* __restrict__ acc) {
    __shared__ float red4[4];
    const float mE = acc[A_SUM_E] * (1.f / 20000.f);
    const float mG = acc[A_SUM_G] * (1.f / 20000.f);
    const int idx = blockIdx.x * 256 + threadIdx.x;

    float sEC = 0.f, sGC = 0.f;
    if (idx < B_ * M_) {
        const float* f = fff + (size_t)idx * 3;
        float E = f[0], F = f[1], G = f[2];
        float A2  = fmaxf(E * G - F * F, 0.f);
        float inv = 1.f / (A2 + EPS_);
        sEC = (E - mE) * (E - mE) * inv;
        sGC = (G - mG) * (G - mG) * inv;
    }
    float rEC = block_sum256(sEC, red4);
    float rGC = block_sum256(sGC, red4);
    if (threadIdx.x == 0) {
        atomicAdd(&acc[A_SUM_EC], rEC);
        atomicAdd(&acc[A_SUM_GC], rGC);
    }
}

// ---- finalize -------------------------------------------------------------
__global__ void finalize_loss(const float* __restrict__ acc,
                              const float* __restrict__ A_gt,
                              float* __restrict__ out) {
    if (threadIdx.x == 0 && blockIdx.x == 0) {
        float L_chd = acc[A_SUM_P2GT] * (1.f / 20000.f)
                    + acc[A_SUM_GT2P] * (1.f / 65536.f);
        float L_mc  = acc[A_SUM_MC] * (1.f / 10000.f);
        float L_sc  = (acc[A_SUM_ST] + acc[A_SUM_F] + acc[A_SUM_EC] + acc[A_SUM_GC])
                      * (1.f / 20000.f);
        float L_olap = 0.f;
        #pragma unroll
        for (int b = 0; b < B_; ++b) {
            float At = acc[A_ASUM0 + b] * (1.f / (float)SPP_);
            float r  = fmaxf(0.f, At - A_gt[b]);
            L_olap += r * r;
        }
        L_olap *= (1.f / (float)B_);
        out[0] = L_chd + L_mc + L_sc + L_olap;
    }
}

extern "C" void kernel_launch(void* const* d_in, const int* in_sizes, int n_in,
                              void* d_out, int out_size, void* d_ws, size_t ws_size,
                              hipStream_t stream) {
    const float* pc_gt   = (const float*)d_in[0];   // (8, 8192, 3)
    const float* pc_pred = (const float*)d_in[1];   // (8, 2500, 3)
    const float* fff     = (const float*)d_in[2];   // (8, 2500, 3)
    const float* A_gt    = (const float*)d_in[3];   // (8,)
    float* ws  = (float*)d_ws;                      // needs ~343 KB
    float* out = (float*)d_out;

    // Sentinel-init min arrays: bytes 0x7F -> float 0x7F7F7F7F ~= 3.39e38.
    hipMemsetAsync(ws, 0x7F, (size_t)(WS_ACC) * sizeof(float), stream);
    hipMemsetAsync(ws + WS_ACC, 0, (size_t)ACC_COUNT * sizeof(float), stream);

    chamfer_p2gt<<<dim3(10, 8, 8), 256, 0, stream>>>(pc_gt, pc_pred, ws + WS_P2GT);
    chamfer_gt2p<<<dim3(32, 8, 4), 256, 0, stream>>>(pc_gt, pc_pred, ws + WS_GT2P);
    reduce_mins <<<128, 256, 0, stream>>>(ws, ws + WS_ACC);
    fff_pass1   <<<79, 256, 0, stream>>>(fff, ws + WS_ACC);
    fff_pass2   <<<79, 256, 0, stream>>>(fff, ws + WS_ACC);
    finalize_loss<<<1, 64, 0, stream>>>(ws + WS_ACC, A_gt, out);
}

// Round 2
// 123.143 us; speedup vs baseline: 1.9857x; 1.9857x over previous
//
#include <hip/hip_runtime.h>

// Problem constants (from reference: B=8, N=8192, M=2500, P=10)
#define B_   8
#define N_   8192
#define M_   2500
#define P_   10
#define SPP_ 250
#define EPS_ 1e-20f

// ws layout (floats):
//   [0 .. 19999]        p2gt per-(b,m) min d^2    (20000)
//   [20000 .. 85535]    gt2p per-(b,n) min d^2    (65536)
//   [85536 .. ]         scalar accumulators
#define WS_P2GT   0
#define WS_GT2P   20000
#define WS_ACC    85536
// accumulator slots
#define A_SUM_P2GT 0
#define A_SUM_GT2P 1
#define A_SUM_E    2
#define A_SUM_G    3
#define A_SUM_MC   4
#define A_SUM_ST   5
#define A_SUM_F    6
#define A_SUM_EC   7
#define A_SUM_GC   8
#define A_ASUM0    9   // 9..16 : per-batch sum of A
#define ACC_COUNT  17

__device__ __forceinline__ float wave_sum64(float v) {
    #pragma unroll
    for (int o = 32; o > 0; o >>= 1) v += __shfl_down(v, o, 64);
    return v;
}

// Block sum over 256 threads (4 waves). Result valid on thread 0.
__device__ __forceinline__ float block_sum256(float v, float* red4) {
    v = wave_sum64(v);
    int wid  = threadIdx.x >> 6;
    int lane = threadIdx.x & 63;
    if (lane == 0) red4[wid] = v;
    __syncthreads();
    float r = 0.f;
    if (threadIdx.x == 0) r = red4[0] + red4[1] + red4[2] + red4[3];
    __syncthreads();  // red4 reusable after return
    return r;
}

// ---- Chamfer: pred -> nearest gt ------------------------------------------
// 4 preds per thread (strided by 625). grid (3, 8, 32), block 256.
// Each z-chunk covers 256 gt points staged in LDS.
__global__ void chamfer_p2gt(const float* __restrict__ gt,
                             const float* __restrict__ pred,
                             float* __restrict__ mins) {
    __shared__ float4 sg[256];
    const int b = blockIdx.y;
    const int z = blockIdx.z;
    const int t = blockIdx.x * 256 + threadIdx.x;   // 0..767, active < 625

    const float* gtb = gt + ((size_t)b * N_ + (size_t)z * 256) * 3;
    {
        const int i = threadIdx.x;
        float gx = gtb[i * 3 + 0];
        float gy = gtb[i * 3 + 1];
        float gz = gtb[i * 3 + 2];
        sg[i] = make_float4(gx, gy, gz, gx * gx + gy * gy + gz * gz);
    }
    __syncthreads();

    if (t < 625) {
        float px[4], py[4], pz[4], pn[4], best[4];
        #pragma unroll
        for (int j = 0; j < 4; ++j) {
            const float* p = pred + ((size_t)b * M_ + t + j * 625) * 3;
            px[j] = p[0]; py[j] = p[1]; pz[j] = p[2];
            pn[j] = px[j] * px[j] + py[j] * py[j] + pz[j] * pz[j];
            best[j] = 3.4e38f;
        }
        #pragma unroll 4
        for (int i = 0; i < 256; ++i) {
            float4 g = sg[i];
            #pragma unroll
            for (int j = 0; j < 4; ++j) {
                float tt = fmaf(g.x, px[j], fmaf(g.y, py[j], g.z * pz[j]));
                float v  = fmaf(-2.f, tt, g.w);   // |g|^2 - 2 p.g
                best[j]  = fminf(best[j], v);
            }
        }
        #pragma unroll
        for (int j = 0; j < 4; ++j) {
            float d = fmaxf(best[j] + pn[j], 0.f);
            atomicMin((unsigned int*)&mins[b * M_ + t + j * 625], __float_as_uint(d));
        }
    }
}

// ---- Chamfer: gt -> nearest pred ------------------------------------------
// 4 gts per thread (strided by 2048). grid (8, 8, 20), block 256.
// Each z-chunk covers 125 pred points staged in LDS.
__global__ void chamfer_gt2p(const float* __restrict__ gt,
                             const float* __restrict__ pred,
                             float* __restrict__ mins) {
    __shared__ float4 sp[125];
    const int b = blockIdx.y;
    const int z = blockIdx.z;
    const int t = blockIdx.x * 256 + threadIdx.x;   // 0..2047, all active

    const float* pb = pred + ((size_t)b * M_ + (size_t)z * 125) * 3;
    if (threadIdx.x < 125) {
        const int i = threadIdx.x;
        float x = pb[i * 3 + 0];
        float y = pb[i * 3 + 1];
        float w = pb[i * 3 + 2];
        sp[i] = make_float4(x, y, w, x * x + y * y + w * w);
    }
    __syncthreads();

    float gx[4], gy[4], gz[4], gn[4], best[4];
    #pragma unroll
    for (int j = 0; j < 4; ++j) {
        const float* g = gt + ((size_t)b * N_ + t + j * 2048) * 3;
        gx[j] = g[0]; gy[j] = g[1]; gz[j] = g[2];
        gn[j] = gx[j] * gx[j] + gy[j] * gy[j] + gz[j] * gz[j];
        best[j] = 3.4e38f;
    }
    #pragma unroll 4
    for (int i = 0; i < 125; ++i) {
        float4 p = sp[i];
        #pragma unroll
        for (int j = 0; j < 4; ++j) {
            float tt = fmaf(p.x, gx[j], fmaf(p.y, gy[j], p.z * gz[j]));
            float v  = fmaf(-2.f, tt, p.w);
            best[j]  = fminf(best[j], v);
        }
    }
    #pragma unroll
    for (int j = 0; j < 4; ++j) {
        float d = fmaxf(best[j] + gn[j], 0.f);
        atomicMin((unsigned int*)&mins[b * N_ + t + j * 2048], __float_as_uint(d));
    }
}

// ---- sum the two min arrays -----------------------------------------------
__global__ void reduce_mins(const float* __restrict__ mins, float* __restrict__ acc) {
    __shared__ float red4[4];
    float s0 = 0.f, s1 = 0.f;
    for (int i = blockIdx.x * blockDim.x + threadIdx.x; i < 85536;
         i += gridDim.x * blockDim.x) {
        float v = mins[i];
        if (i < 20000) s0 += v; else s1 += v;
    }
    float b0 = block_sum256(s0, red4);
    float b1 = block_sum256(s1, red4);
    if (threadIdx.x == 0) {
        atomicAdd(&acc[A_SUM_P2GT], b0);
        atomicAdd(&acc[A_SUM_GT2P], b1);
    }
}

// ---- FFF pass 1: everything not needing global means ----------------------
// grid ceil(20000/256)=79
__global__ void fff_pass1(const float* __restrict__ fff, float* __restrict__ acc) {
    __shared__ float red4[4];
    __shared__ float sA[B_];
    const int idx = blockIdx.x * 256 + threadIdx.x;

    if (threadIdx.x < B_) sA[threadIdx.x] = 0.f;
    __syncthreads();

    float sE = 0.f, sG = 0.f, sMC = 0.f, sST = 0.f, sF = 0.f;
    if (idx < B_ * M_) {
        const int b = idx / M_;
        const int m = idx - b * M_;
        const float* f = fff + (size_t)idx * 3;
        float E = f[0], F = f[1], G = f[2];
        sE = E; sG = G;
        float A2  = fmaxf(E * G - F * F, 0.f);
        float inv = 1.f / (A2 + EPS_);
        sST = (E - G) * (E - G) * inv;
        sF  = F * F * inv;
        atomicAdd(&sA[b], sqrtf(A2));
        if ((b & 1) == 0) {
            const float* f2 = fff + ((size_t)(b + 1) * M_ + m) * 3;
            float dE = E - f2[0], dF = F - f2[1], dG = G - f2[2];
            sMC = dE * dE + 2.f * dF * dF + dG * dG;
        }
    }
    float rE  = block_sum256(sE, red4);
    float rG  = block_sum256(sG, red4);
    float rMC = block_sum256(sMC, red4);
    float rST = block_sum256(sST, red4);
    float rF  = block_sum256(sF, red4);
    if (threadIdx.x == 0) {
        atomicAdd(&acc[A_SUM_E],  rE);
        atomicAdd(&acc[A_SUM_G],  rG);
        atomicAdd(&acc[A_SUM_MC], rMC);
        atomicAdd(&acc[A_SUM_ST], rST);
        atomicAdd(&acc[A_SUM_F],  rF);
    }
    __syncthreads();  // all sA atomics done
    if (threadIdx.x < B_ && sA[threadIdx.x] != 0.f)
        atomicAdd(&acc[A_ASUM0 + threadIdx.x], sA[threadIdx.x]);
}

// ---- FFF pass 2: centered E/G terms (needs global means from pass 1) ------
__global__ void fff_pass2(const float* __restrict__ fff, float* __restrict__ acc) {
    __shared__ float red4[4];
    const float mE = acc[A_SUM_E] * (1.f / 20000.f);
    const float mG = acc[A_SUM_G] * (1.f / 20000.f);
    const int idx = blockIdx.x * 256 + threadIdx.x;

    float sEC = 0.f, sGC = 0.f;
    if (idx < B_ * M_) {
        const float* f = fff + (size_t)idx * 3;
        float E = f[0], F = f[1], G = f[2];
        float A2  = fmaxf(E * G - F * F, 0.f);
        float inv = 1.f / (A2 + EPS_);
        sEC = (E - mE) * (E - mE) * inv;
        sGC = (G - mG) * (G - mG) * inv;
    }
    float rEC = block_sum256(sEC, red4);
    float rGC = block_sum256(sGC, red4);
    if (threadIdx.x == 0) {
        atomicAdd(&acc[A_SUM_EC], rEC);
        atomicAdd(&acc[A_SUM_GC], rGC);
    }
}

// ---- finalize -------------------------------------------------------------
__global__ void finalize_loss(const float* __restrict__ acc,
                              const float* __restrict__ A_gt,
                              float* __restrict__ out) {
    if (threadIdx.x == 0 && blockIdx.x == 0) {
        float L_chd = acc[A_SUM_P2GT] * (1.f / 20000.f)
                    + acc[A_SUM_GT2P] * (1.f / 65536.f);
        float L_mc  = acc[A_SUM_MC] * (1.f / 10000.f);
        float L_sc  = (acc[A_SUM_ST] + acc[A_SUM_F] + acc[A_SUM_EC] + acc[A_SUM_GC])
                      * (1.f / 20000.f);
        float L_olap = 0.f;
        #pragma unroll
        for (int b = 0; b < B_; ++b) {
            float At = acc[A_ASUM0 + b] * (1.f / (float)SPP_);
            float r  = fmaxf(0.f, At - A_gt[b]);
            L_olap += r * r;
        }
        L_olap *= (1.f / (float)B_);
        out[0] = L_chd + L_mc + L_sc + L_olap;
    }
}

extern "C" void kernel_launch(void* const* d_in, const int* in_sizes, int n_in,
                              void* d_out, int out_size, void* d_ws, size_t ws_size,
                              hipStream_t stream) {
    const float* pc_gt   = (const float*)d_in[0];   // (8, 8192, 3)
    const float* pc_pred = (const float*)d_in[1];   // (8, 2500, 3)
    const float* fff     = (const float*)d_in[2];   // (8, 2500, 3)
    const float* A_gt    = (const float*)d_in[3];   // (8,)
    float* ws  = (float*)d_ws;                      // needs ~343 KB
    float* out = (float*)d_out;

    // Sentinel-init min arrays: bytes 0x7F -> float 0x7F7F7F7F ~= 3.39e38.
    hipMemsetAsync(ws, 0x7F, (size_t)(WS_ACC) * sizeof(float), stream);
    hipMemsetAsync(ws + WS_ACC, 0, (size_t)ACC_COUNT * sizeof(float), stream);

    chamfer_p2gt<<<dim3(3, 8, 32), 256, 0, stream>>>(pc_gt, pc_pred, ws + WS_P2GT);
    chamfer_gt2p<<<dim3(8, 8, 20), 256, 0, stream>>>(pc_gt, pc_pred, ws + WS_GT2P);
    reduce_mins <<<128, 256, 0, stream>>>(ws, ws + WS_ACC);
    fff_pass1   <<<79, 256, 0, stream>>>(fff, ws + WS_ACC);
    fff_pass2   <<<79, 256, 0, stream>>>(fff, ws + WS_ACC);
    finalize_loss<<<1, 64, 0, stream>>>(ws + WS_ACC, A_gt, out);
}

// Round 3
// 119.374 us; speedup vs baseline: 2.0484x; 1.0316x over previous
//
#include <hip/hip_runtime.h>

// Problem constants (from reference: B=8, N=8192, M=2500, P=10)
#define B_   8
#define N_   8192
#define M_   2500
#define SPP_ 250
#define EPS_ 1e-20f

// ---- chunking ----
#define ZP_  64      // p2gt: gt split into 64 chunks of 128
#define ZG_  20      // gt2p: pred split into 20 chunks of 125
// blocks per role in fused_main
#define NB_P2GT  (ZP_ * B_)          // 512  (1 x-block covers 2500 preds, J=10)
#define NB_GT2P  (ZG_ * B_ * 4)      // 640  (4 x-blocks cover 8192 gts, J=8)
#define NB_FFF1  79
#define NB_MAIN  (NB_P2GT + NB_GT2P + NB_FFF1)   // 1231

// fused_reduce roles
#define NB_RGT2P 256                 // 65536 outputs
#define NB_RP2GT 79                  // 20000 outputs (79*256=20224)
#define NB_FFF2  79
#define NB_RED   (NB_RGT2P + NB_RP2GT + NB_FFF2) // 414

// ---- ws layout (floats) ----
#define WS_P2GT  0                            // ZP_*20000 partial mins
#define WS_GT2P  (ZP_ * 20000)                // ZG_*65536 partial mins
#define WS_ACC   (WS_GT2P + ZG_ * 65536)      // accumulators
// acc slots
#define A_SUM_P2GT 0
#define A_SUM_GT2P 1
#define A_SUM_E    2
#define A_SUM_G    3
#define A_SUM_MC   4
#define A_SUM_ST   5
#define A_SUM_F    6
#define A_SUM_EC   7
#define A_SUM_GC   8
#define A_ASUM0    9    // 9..16 per-batch sum of A
#define A_CNT      17   // arrival counter (uint)
#define ACC_COUNT  18

__device__ __forceinline__ float wave_sum64(float v) {
    #pragma unroll
    for (int o = 32; o > 0; o >>= 1) v += __shfl_down(v, o, 64);
    return v;
}

__device__ __forceinline__ float block_sum256(float v, float* red4) {
    v = wave_sum64(v);
    int wid  = threadIdx.x >> 6;
    int lane = threadIdx.x & 63;
    if (lane == 0) red4[wid] = v;
    __syncthreads();
    float r = 0.f;
    if (threadIdx.x == 0) r = red4[0] + red4[1] + red4[2] + red4[3];
    __syncthreads();
    return r;
}

// ============================================================================
// Kernel 1: both chamfer directions + fff pass 1, role-dispatched by blockIdx.
// Chamfer stores NON-ATOMIC per-z-chunk partial minima (each slot written by
// exactly one thread) -> no sentinel memset, no atomicMin.
// LDS points pre-scaled by -2 so inner loop = 3 FMA + 1 min per pair.
// ============================================================================
__global__ void __launch_bounds__(256) fused_main(
        const float* __restrict__ gt, const float* __restrict__ pred,
        const float* __restrict__ fff, float* __restrict__ ws) {
    __shared__ float4 sbuf[128];
    __shared__ float  red4[4];
    __shared__ float  sA[B_];
    const int bid = blockIdx.x;
    const int tid = threadIdx.x;
    float* acc = ws + WS_ACC;

    if (bid < NB_P2GT) {
        // ---- pred -> nearest gt.  b = bid&7, z = bid>>3 (gt chunk of 128).
        const int b = bid & 7;
        const int z = bid >> 3;
        const float* gtb = gt + ((size_t)b * N_ + (size_t)z * 128) * 3;
        if (tid < 128) {
            float gx = gtb[tid * 3 + 0];
            float gy = gtb[tid * 3 + 1];
            float gz = gtb[tid * 3 + 2];
            sbuf[tid] = make_float4(-2.f * gx, -2.f * gy, -2.f * gz,
                                    gx * gx + gy * gy + gz * gz);
        }
        __syncthreads();

        // J=10 preds per thread: idx = tid + 256*j covers [0,2560) -> mask 2500
        float px[10], py[10], pz[10], pn[10], best[10];
        #pragma unroll
        for (int j = 0; j < 10; ++j) {
            int idx = tid + 256 * j;
            int ic  = idx < M_ ? idx : M_ - 1;            // clamp (dup work ok)
            const float* p = pred + ((size_t)b * M_ + ic) * 3;
            px[j] = p[0]; py[j] = p[1]; pz[j] = p[2];
            pn[j] = px[j] * px[j] + py[j] * py[j] + pz[j] * pz[j];
            best[j] = 3.4e38f;
        }
        #pragma unroll 2
        for (int i = 0; i < 128; ++i) {
            float4 g = sbuf[i];
            #pragma unroll
            for (int j = 0; j < 10; ++j) {
                float v = fmaf(g.x, px[j], fmaf(g.y, py[j], fmaf(g.z, pz[j], g.w)));
                best[j] = fminf(best[j], v);
            }
        }
        float* dst = ws + WS_P2GT + (size_t)z * 20000 + b * M_;
        #pragma unroll
        for (int j = 0; j < 10; ++j) {
            int idx = tid + 256 * j;
            if (idx < M_) dst[idx] = fmaxf(best[j] + pn[j], 0.f);
        }
    } else if (bid < NB_P2GT + NB_GT2P) {
        // ---- gt -> nearest pred.  decode: b, x (gt quarter), z (pred chunk of 125)
        const int r = bid - NB_P2GT;      // [0,640)
        const int b = r & 7;
        const int q = r >> 3;             // [0,80)
        const int x = q & 3;
        const int z = q >> 2;             // [0,20)
        const float* pb = pred + ((size_t)b * M_ + (size_t)z * 125) * 3;
        if (tid < 125) {
            float vx = pb[tid * 3 + 0];
            float vy = pb[tid * 3 + 1];
            float vz = pb[tid * 3 + 2];
            sbuf[tid] = make_float4(-2.f * vx, -2.f * vy, -2.f * vz,
                                    vx * vx + vy * vy + vz * vz);
        }
        __syncthreads();

        const int t = x * 256 + tid;      // [0,1024)
        float gx[8], gy[8], gz[8], gn[8], best[8];
        #pragma unroll
        for (int j = 0; j < 8; ++j) {
            int idx = t + 1024 * j;       // covers [0,8192) exactly
            const float* g = gt + ((size_t)b * N_ + idx) * 3;
            gx[j] = g[0]; gy[j] = g[1]; gz[j] = g[2];
            gn[j] = gx[j] * gx[j] + gy[j] * gy[j] + gz[j] * gz[j];
            best[j] = 3.4e38f;
        }
        #pragma unroll 2
        for (int i = 0; i < 125; ++i) {
            float4 p = sbuf[i];
            #pragma unroll
            for (int j = 0; j < 8; ++j) {
                float v = fmaf(p.x, gx[j], fmaf(p.y, gy[j], fmaf(p.z, gz[j], p.w)));
                best[j] = fminf(best[j], v);
            }
        }
        float* dst = ws + WS_GT2P + (size_t)z * 65536 + b * N_;
        #pragma unroll
        for (int j = 0; j < 8; ++j) {
            int idx = t + 1024 * j;
            dst[idx] = fmaxf(best[j] + gn[j], 0.f);
        }
    } else {
        // ---- fff pass 1
        const int i = (bid - NB_P2GT - NB_GT2P) * 256 + tid;
        if (tid < B_) sA[tid] = 0.f;
        __syncthreads();

        float sE = 0.f, sG = 0.f, sMC = 0.f, sST = 0.f, sF = 0.f;
        if (i < B_ * M_) {
            const int b = i / M_;
            const int m = i - b * M_;
            const float* f = fff + (size_t)i * 3;
            float E = f[0], F = f[1], G = f[2];
            sE = E; sG = G;
            float A2  = fmaxf(E * G - F * F, 0.f);
            float inv = 1.f / (A2 + EPS_);
            sST = (E - G) * (E - G) * inv;
            sF  = F * F * inv;
            atomicAdd(&sA[b], sqrtf(A2));
            if ((b & 1) == 0) {
                const float* f2 = fff + ((size_t)(b + 1) * M_ + m) * 3;
                float dE = E - f2[0], dF = F - f2[1], dG = G - f2[2];
                sMC = dE * dE + 2.f * dF * dF + dG * dG;
            }
        }
        float rE  = block_sum256(sE,  red4);
        float rG  = block_sum256(sG,  red4);
        float rMC = block_sum256(sMC, red4);
        float rST = block_sum256(sST, red4);
        float rF  = block_sum256(sF,  red4);
        if (tid == 0) {
            atomicAdd(&acc[A_SUM_E],  rE);
            atomicAdd(&acc[A_SUM_G],  rG);
            atomicAdd(&acc[A_SUM_MC], rMC);
            atomicAdd(&acc[A_SUM_ST], rST);
            atomicAdd(&acc[A_SUM_F],  rF);
        }
        __syncthreads();
        if (tid < B_ && sA[tid] != 0.f)
            atomicAdd(&acc[A_ASUM0 + tid], sA[tid]);
    }
}

// ============================================================================
// Kernel 2: min-over-z reduction for both directions + fff pass 2 + finalize.
// Last block (device-scope arrival counter) computes the scalar loss.
// ============================================================================
__global__ void __launch_bounds__(256) fused_reduce(
        const float* __restrict__ fff, const float* __restrict__ A_gt,
        float* __restrict__ ws, float* __restrict__ out) {
    __shared__ float red4[4];
    const int bid = blockIdx.x;
    const int tid = threadIdx.x;
    float* acc = ws + WS_ACC;

    if (bid < NB_RGT2P) {
        // ---- gt2p: min over 20 z-chunks, sum
        const int o = bid * 256 + tid;    // [0,65536)
        const float* src = ws + WS_GT2P + o;
        float m = src[0];
        #pragma unroll
        for (int z = 1; z < ZG_; ++z) m = fminf(m, src[(size_t)z * 65536]);
        float r = block_sum256(m, red4);
        if (tid == 0) atomicAdd(&acc[A_SUM_GT2P], r);
    } else if (bid < NB_RGT2P + NB_RP2GT) {
        // ---- p2gt: min over 64 z-chunks, sum
        const int o = (bid - NB_RGT2P) * 256 + tid;   // [0,20224)
        float s = 0.f;
        if (o < 20000) {
            const float* src = ws + WS_P2GT + o;
            float m = src[0];
            #pragma unroll
            for (int z = 1; z < ZP_; ++z) m = fminf(m, src[(size_t)z * 20000]);
            s = m;
        }
        float r = block_sum256(s, red4);
        if (tid == 0) atomicAdd(&acc[A_SUM_P2GT], r);
    } else {
        // ---- fff pass 2 (means from kernel-1 accumulators; safe across dispatch)
        const float mE = acc[A_SUM_E] * (1.f / 20000.f);
        const float mG = acc[A_SUM_G] * (1.f / 20000.f);
        const int i = (bid - NB_RGT2P - NB_RP2GT) * 256 + tid;
        float sEC = 0.f, sGC = 0.f;
        if (i < B_ * M_) {
            const float* f = fff + (size_t)i * 3;
            float E = f[0], F = f[1], G = f[2];
            float A2  = fmaxf(E * G - F * F, 0.f);
            float inv = 1.f / (A2 + EPS_);
            sEC = (E - mE) * (E - mE) * inv;
            sGC = (G - mG) * (G - mG) * inv;
        }
        float rEC = block_sum256(sEC, red4);
        float rGC = block_sum256(sGC, red4);
        if (tid == 0) {
            atomicAdd(&acc[A_SUM_EC], rEC);
            atomicAdd(&acc[A_SUM_GC], rGC);
        }
    }

    // ---- arrival counter; last block finalizes
    if (tid == 0) {
        __threadfence();
        unsigned int* cnt = (unsigned int*)&acc[A_CNT];
        unsigned int old = __hip_atomic_fetch_add(cnt, 1u, __ATOMIC_ACQ_REL,
                                                  __HIP_MEMORY_SCOPE_AGENT);
        if (old == (unsigned int)(NB_RED - 1)) {
            float a[17];
            #pragma unroll
            for (int i = 0; i < 17; ++i)
                a[i] = __hip_atomic_load(&acc[i], __ATOMIC_RELAXED,
                                         __HIP_MEMORY_SCOPE_AGENT);
            float L_chd = a[A_SUM_P2GT] * (1.f / 20000.f)
                        + a[A_SUM_GT2P] * (1.f / 65536.f);
            float L_mc  = a[A_SUM_MC] * (1.f / 10000.f);
            float L_sc  = (a[A_SUM_ST] + a[A_SUM_F] + a[A_SUM_EC] + a[A_SUM_GC])
                          * (1.f / 20000.f);
            float L_olap = 0.f;
            #pragma unroll
            for (int b = 0; b < B_; ++b) {
                float At = a[A_ASUM0 + b] * (1.f / (float)SPP_);
                float r  = fmaxf(0.f, At - A_gt[b]);
                L_olap += r * r;
            }
            L_olap *= (1.f / (float)B_);
            out[0] = L_chd + L_mc + L_sc + L_olap;
        }
    }
}

extern "C" void kernel_launch(void* const* d_in, const int* in_sizes, int n_in,
                              void* d_out, int out_size, void* d_ws, size_t ws_size,
                              hipStream_t stream) {
    const float* pc_gt   = (const float*)d_in[0];   // (8, 8192, 3)
    const float* pc_pred = (const float*)d_in[1];   // (8, 2500, 3)
    const float* fff     = (const float*)d_in[2];   // (8, 2500, 3)
    const float* A_gt    = (const float*)d_in[3];   // (8,)
    float* ws  = (float*)d_ws;                      // ~10.4 MB used
    float* out = (float*)d_out;

    // zero the 18-slot accumulator block only (72 B)
    hipMemsetAsync(ws + WS_ACC, 0, ACC_COUNT * sizeof(float), stream);
    fused_main  <<<NB_MAIN, 256, 0, stream>>>(pc_gt, pc_pred, fff, ws);
    fused_reduce<<<NB_RED,  256, 0, stream>>>(fff, A_gt, ws, out);
}